// Round 9
// baseline (92.323 us; speedup 1.0000x reference)
//
#include <hip/hip_runtime.h>
#include <cstdint>

#define SEQ    8192
#define DIN    1024
#define DOUT   128
#define NSPLIT 8
#define KVTILE 64
#define QTILE  128
// Q is pre-scaled by 1/sqrt(128) * log2(e) at the QKV GEMM epilogue, so the
// attn kernel works entirely in log2-units (exp2, no LOG2E muls).
#define QK_SCALE 0.1275174246f
#define RESCALE_THR 8.0f

typedef unsigned short u16;
typedef __bf16 bf16x8 __attribute__((ext_vector_type(8)));
typedef float  f32x4  __attribute__((ext_vector_type(4)));
typedef unsigned short u16x8 __attribute__((ext_vector_type(8)));
typedef unsigned short u16x4 __attribute__((ext_vector_type(4)));

// f32 -> bf16 via native cast (compiler emits v_cvt_pk_bf16_f32, RNE)
__device__ __forceinline__ u16 bfc(float f) {
  return __builtin_bit_cast(u16, (__bf16)f);
}
__device__ __forceinline__ float bf2f(u16 u) {
  union { uint32_t u; float f; } c; c.u = ((uint32_t)u) << 16; return c.f;
}

__device__ __forceinline__ bf16x8 ldsu8(const u16* base, int byteoff) {
  return __builtin_bit_cast(bf16x8,
    *reinterpret_cast<const u16x8*>(reinterpret_cast<const char*>(base) + byteoff));
}
__device__ __forceinline__ bf16x8 glbu8(const u16* p) {
  return __builtin_bit_cast(bf16x8, *reinterpret_cast<const u16x8*>(p));
}

// async global->LDS DMA, 16B per lane; LDS dest = wave-uniform base + lane*16.
__device__ __forceinline__ void gload_lds16(const void* g, void* l) {
  __builtin_amdgcn_global_load_lds(
      (const __attribute__((address_space(1))) void*)g,
      (__attribute__((address_space(3))) void*)l, 16, 0, 0);
}

// ---------------------------------------------------------------- kernel 0
// W [1024][128] fp32  ->  Wt [3][128][1024] bf16 (transposed)
__global__ __launch_bounds__(256) void k_wtrans(const float* __restrict__ wq,
                                                const float* __restrict__ wk,
                                                const float* __restrict__ wv,
                                                u16* __restrict__ Wt) {
  const float* w = (blockIdx.y == 0) ? wq : (blockIdx.y == 1) ? wk : wv;
  int idx = blockIdx.x * 256 + threadIdx.x;      // over DIN*DOUT
  int k = idx >> 7, n = idx & 127;
  Wt[(size_t)blockIdx.y * (DOUT * DIN) + (size_t)n * DIN + k] = bfc(w[idx]);
}

// ---------------------------------------------------------------- kernel 0b
// X fp32 [8192][1024] -> Xb bf16 [8192][1024], coalesced. 8 elems/thread.
__global__ __launch_bounds__(256) void k_xcast(const float* __restrict__ x,
                                               u16* __restrict__ Xb) {
  size_t base = ((size_t)blockIdx.x * 256 + threadIdx.x) * 8;
  float4 lo = *reinterpret_cast<const float4*>(x + base);
  float4 hi = *reinterpret_cast<const float4*>(x + base + 4);
  u16x8 v = { bfc(lo.x), bfc(lo.y), bfc(lo.z), bfc(lo.w),
              bfc(hi.x), bfc(hi.y), bfc(hi.z), bfc(hi.w) };
  *reinterpret_cast<u16x8*>(Xb + base) = v;
}

// ---------------------------------------------------------------- kernel 1
// GEMM C[8192][384] = Xb[8192][1024] * Wt^T.  (byte-identical to round 7)
__global__ __launch_bounds__(256, 2) void k_gemm(const u16* __restrict__ Xb,
                                                 const u16* __restrict__ Wt,
                                                 u16* __restrict__ Q,
                                                 u16* __restrict__ K,
                                                 u16* __restrict__ Vt) {
  __shared__ __attribute__((aligned(16))) u16 As[2][64 * 128];   // 2x16 KB
  __shared__ __attribute__((aligned(16))) u16 Bs[2][96 * 128];   // 2x24 KB
  const int tid  = threadIdx.x;
  const int lane = tid & 63, wave = tid >> 6;
  const int lm   = lane & 15, g = lane >> 4;
  const int wm   = wave >> 1, wn = wave & 1;     // 2x2 wave grid
  const int m0   = blockIdx.x * 64;
  const int n0   = blockIdx.y * 96;
  const int swzr = (lm & 7) << 4;

  const int trow = tid >> 4;                     // 0..15
  const int tswz = ((tid & 15) << 4) ^ ((trow & 7) << 4);
  const char* baseA = (const char*)Xb + (size_t)(m0 + trow) * 2048 + tswz;
  const char* baseB = (const char*)Wt + (size_t)(n0 + trow) * 2048 + tswz;

  auto stage = [&](int buf, int kc) {
    const int kb = kc * 256;                     // 128 k * 2B
#pragma unroll
    for (int i = 0; i < 4; ++i)                  // A: 64 rows = 4 issues
      gload_lds16(baseA + kb + i * 32768, &As[buf][i * 2048 + wave * 512]);
#pragma unroll
    for (int j = 0; j < 6; ++j)                  // B: 96 rows = 6 issues
      gload_lds16(baseB + kb + j * 32768, &Bs[buf][j * 2048 + wave * 512]);
  };

  f32x4 acc[2][3];
#pragma unroll
  for (int s = 0; s < 2; ++s)
#pragma unroll
    for (int nb = 0; nb < 3; ++nb) acc[s][nb] = (f32x4){0.f, 0.f, 0.f, 0.f};

  auto compute = [&](int buf) {
    const u16* As_ = As[buf];
    const u16* Bs_ = Bs[buf];
    bf16x8 a[2][4], b[3][4];
#pragma unroll
    for (int s = 0; s < 2; ++s)
#pragma unroll
      for (int t = 0; t < 4; ++t)
        a[s][t] = ldsu8(As_, (wm * 32 + s * 16 + lm) * 256 +
                             ((t * 64 + 16 * g) ^ swzr));
#pragma unroll
    for (int nb = 0; nb < 3; ++nb)
#pragma unroll
      for (int t = 0; t < 4; ++t)
        b[nb][t] = ldsu8(Bs_, (wn * 48 + nb * 16 + lm) * 256 +
                              ((t * 64 + 16 * g) ^ swzr));
#pragma unroll
    for (int s = 0; s < 2; ++s)
#pragma unroll
      for (int nb = 0; nb < 3; ++nb)
#pragma unroll
        for (int t = 0; t < 4; ++t)
          acc[s][nb] = __builtin_amdgcn_mfma_f32_16x16x32_bf16(
              a[s][t], b[nb][t], acc[s][nb], 0, 0, 0);
  };

  stage(0, 0);
  asm volatile("s_waitcnt vmcnt(0)" ::: "memory");
  __syncthreads();

#pragma unroll
  for (int kc = 0; kc < 8; kc += 2) {
    if (kc + 1 < 8) stage(1, kc + 1);
    compute(0);
    asm volatile("s_waitcnt vmcnt(0)" ::: "memory");
    __syncthreads();
    if (kc + 2 < 8) stage(0, kc + 2);
    compute(1);
    asm volatile("s_waitcnt vmcnt(0)" ::: "memory");
    __syncthreads();
  }

  // epilogue: C/D layout col=lane&15, row=(lane>>4)*4+reg  [HW-verified]
#pragma unroll
  for (int s = 0; s < 2; ++s)
#pragma unroll
    for (int nb = 0; nb < 3; ++nb) {
      int n = n0 + wn * 48 + nb * 16 + lm;
      int which = n >> 7, col = n & 127;         // uniform per nb
#pragma unroll
      for (int r = 0; r < 4; ++r) {
        int m = m0 + wm * 32 + s * 16 + g * 4 + r;
        if (which == 0)       Q[(size_t)m * DOUT + col] = bfc(acc[s][nb][r] * QK_SCALE);
        else if (which == 1)  K[(size_t)m * DOUT + col] = bfc(acc[s][nb][r]);
        else                  Vt[(size_t)col * SEQ + m] = bfc(acc[s][nb][r]);
      }
    }
}

// ---------------------------------------------------------------- kernel 2
// Flash attention partials.  Round-8 structure (Q-tile 128, 8 waves, dbuf
// gload_lds staging) + this round:
//  - flat 1-D grid, split = bid&7  -> all blocks of a split on one XCD
//    (linear dispatch round-robins XCDs), K/V L2-local per XCD
//  - staging pointers hoisted out of the loop (+= const per tile)
//  - per-lane l partial; cross-lane l reduce deferred to epilogue
//    (removes 2 shuffles + lgkm wait per iter from the serial chain)
//  - setprio(1) around both MFMA clusters (T5; 8 role-diverse waves)
__global__ __launch_bounds__(512) void k_attn(const u16* __restrict__ Q,
                                              const u16* __restrict__ K,
                                              const u16* __restrict__ Vt,
                                              u16* __restrict__ Op,
                                              float* __restrict__ Mb,
                                              float* __restrict__ Lb) {
  __shared__ __attribute__((aligned(16))) u16 Ks[2][64 * 128];    // 2x16 KB
  __shared__ __attribute__((aligned(16))) u16 Vts[2][128 * 64];   // 2x16 KB
  __shared__ __attribute__((aligned(16))) u16 Ps[8][16 * 64];     //  16 KB
  const int tid  = threadIdx.x;
  const int lane = tid & 63, wave = tid >> 6;       // wave 0..7
  const int lm   = lane & 15, g = lane >> 4;
  const int bid  = blockIdx.x;
  const int split = bid & 7;                        // XCD-local split
  const int m0   = (bid >> 3) * QTILE;
  const int kvbase = split * (SEQ / NSPLIT);
  const int NIT = (SEQ / NSPLIT) / KVTILE;          // 16

  // hoisted staging pointers (advance by const per tile)
  const int krow0 = wave * 8 + (lane >> 4);
  const int krow1 = krow0 + 4;
  const int vrow0 = wave * 16 + (lane >> 3);
  const int vrow1 = vrow0 + 8;
  const char* gk0 = (const char*)K + ((size_t)(kvbase + krow0) << 8) +
                    (((lane & 15) << 4) ^ ((krow0 & 7) << 4));
  const char* gk1 = (const char*)K + ((size_t)(kvbase + krow1) << 8) +
                    (((lane & 15) << 4) ^ ((krow1 & 7) << 4));
  const char* gv0 = (const char*)Vt + (size_t)vrow0 * (SEQ * 2) +
                    (size_t)kvbase * 2 +
                    (((lane & 7) << 4) ^ ((vrow0 & 7) << 4));
  const char* gv1 = (const char*)Vt + (size_t)vrow1 * (SEQ * 2) +
                    (size_t)kvbase * 2 +
                    (((lane & 7) << 4) ^ ((vrow1 & 7) << 4));

  auto stage = [&](int buf) {
    gload_lds16(gk0, &Ks[buf][wave * 1024]);
    gload_lds16(gk1, &Ks[buf][wave * 1024 + 512]);
    gload_lds16(gv0, &Vts[buf][wave * 1024]);
    gload_lds16(gv1, &Vts[buf][wave * 1024 + 512]);
  };
  auto advance = [&]() {
    gk0 += KVTILE * 256; gk1 += KVTILE * 256;   // 64 rows * 256B
    gv0 += KVTILE * 2;   gv1 += KVTILE * 2;     // 64 cols * 2B
  };

  bf16x8 qf[4];
  stage(0);
  advance();
  {
    const u16* qp = Q + (size_t)(m0 + wave * 16 + lm) * DOUT + 8 * g;
#pragma unroll
    for (int t = 0; t < 4; ++t) qf[t] = glbu8(qp + t * 32);
  }
  asm volatile("s_waitcnt vmcnt(0)" ::: "memory");
  __syncthreads();

  f32x4 o[8];
#pragma unroll
  for (int nb = 0; nb < 8; ++nb) o[nb] = (f32x4){0.f, 0.f, 0.f, 0.f};
  float mr = -1e30f, lr = 0.f;   // lane-local; lr is a per-lane PARTIAL sum

  u16* pw = Ps[wave];
  char* pwb = reinterpret_cast<char*>(pw) + lm * 128;
  const int pswz = (lm & 7) << 4;
  int cur = 0;

  for (int it = 0; it < NIT; ++it) {
    if (it + 1 < NIT) { stage(cur ^ 1); advance(); }

    const u16* ks = Ks[cur];
    const u16* vs = Vts[cur];

    // ---- S^T = K Q^T  (swapped operands; lane owns q-row m0+wave*16+lm)
    f32x4 s[4];
    __builtin_amdgcn_s_setprio(1);
#pragma unroll
    for (int cb = 0; cb < 4; ++cb) {
      f32x4 a = (f32x4){0.f, 0.f, 0.f, 0.f};
      int krow = cb * 16 + lm;
#pragma unroll
      for (int t = 0; t < 4; ++t) {
        bf16x8 b = ldsu8(ks, krow * 256 +
                             (((t * 32 + 8 * g) * 2) ^ ((krow & 7) << 4)));
        a = __builtin_amdgcn_mfma_f32_16x16x32_bf16(b, qf[t], a, 0, 0, 0);
      }
      s[cb] = a;            // log2-units (Q pre-scaled)
    }
    __builtin_amdgcn_s_setprio(0);

    // ---- row max: in-lane tree + 2 shuffles (only the max needs syncing)
    float c0 = fmaxf(fmaxf(s[0][0], s[0][1]), fmaxf(s[0][2], s[0][3]));
    float c1 = fmaxf(fmaxf(s[1][0], s[1][1]), fmaxf(s[1][2], s[1][3]));
    float c2 = fmaxf(fmaxf(s[2][0], s[2][1]), fmaxf(s[2][2], s[2][3]));
    float c3 = fmaxf(fmaxf(s[3][0], s[3][1]), fmaxf(s[3][2], s[3][3]));
    float rm = fmaxf(fmaxf(c0, c1), fmaxf(c2, c3));
    rm = fmaxf(rm, __shfl_xor(rm, 16));
    rm = fmaxf(rm, __shfl_xor(rm, 32));

    if (__any(rm - mr > RESCALE_THR)) {   // first tile + rare growth
      float mn = fmaxf(mr, rm);
      float alpha = exp2f(mr - mn);
      mr = mn;
      lr *= alpha;                        // per-lane partial scales the same
#pragma unroll
      for (int nb = 0; nb < 8; ++nb) o[nb] *= alpha;
    }

    // ---- P = exp2(S - m); write b64 per cb; lr accumulates lane-locally
    float rsum = 0.f;
#pragma unroll
    for (int cb = 0; cb < 4; ++cb) {
      float p0 = exp2f(s[cb][0] - mr);
      float p1 = exp2f(s[cb][1] - mr);
      float p2 = exp2f(s[cb][2] - mr);
      float p3 = exp2f(s[cb][3] - mr);
      u16x4 w = { bfc(p0), bfc(p1), bfc(p2), bfc(p3) };
      *reinterpret_cast<u16x4*>(pwb + ((cb * 32 + g * 8) ^ pswz)) = w;
      rsum += (p0 + p1) + (p2 + p3);
    }
    lr += rsum;                           // cross-lane reduce deferred to end

    asm volatile("s_waitcnt lgkmcnt(0)" ::: "memory");
    __builtin_amdgcn_sched_barrier(0);

    // ---- O^T += V^T P
    __builtin_amdgcn_s_setprio(1);
#pragma unroll
    for (int t = 0; t < 2; ++t) {
      bf16x8 pb = ldsu8(pw, lm * 128 + ((t * 64 + g * 16) ^ pswz));
#pragma unroll
      for (int nb = 0; nb < 8; ++nb) {
        int vrow = nb * 16 + lm;
        bf16x8 vb = ldsu8(vs, vrow * 128 +
                              (((t * 32 + 8 * g) * 2) ^ ((vrow & 7) << 4)));
        o[nb] = __builtin_amdgcn_mfma_f32_16x16x32_bf16(vb, pb, o[nb], 0, 0, 0);
      }
    }
    __builtin_amdgcn_s_setprio(0);

    asm volatile("s_waitcnt vmcnt(0)" ::: "memory");
    __syncthreads();
    cur ^= 1;
  }

  // ---- epilogue: finish l reduction (butterfly over the 4 lanes of a row)
  lr += __shfl_xor(lr, 16);
  lr += __shfl_xor(lr, 32);

  // store partials: lane holds O[q=m0+wave*16+lm][d=nb*16+g*4+r]
  const size_t ob = (size_t)split * SEQ * DOUT;
  const int m = m0 + wave * 16 + lm;
#pragma unroll
  for (int nb = 0; nb < 8; ++nb) {
    u16x4 w = { bfc(o[nb][0]), bfc(o[nb][1]), bfc(o[nb][2]), bfc(o[nb][3]) };
    *reinterpret_cast<u16x4*>(Op + ob + (size_t)m * DOUT + nb * 16 + g * 4) = w;
  }
  if (g == 0) {
    Mb[split * SEQ + m] = mr;   // log2-units
    Lb[split * SEQ + m] = lr;
  }
}

// ---------------------------------------------------------------- kernel 3
__global__ __launch_bounds__(256) void k_combine(const u16* __restrict__ Op,
                                                 const float* __restrict__ Mb,
                                                 const float* __restrict__ Lb,
                                                 float* __restrict__ out) {
  int idx = blockIdx.x * 256 + threadIdx.x;   // over SEQ*DOUT
  int srow = idx >> 7;
  float M = -1e30f;
#pragma unroll
  for (int s = 0; s < NSPLIT; ++s) M = fmaxf(M, Mb[s * SEQ + srow]);
  float num = 0.f, den = 0.f;
  const size_t st = (size_t)SEQ * DOUT;
#pragma unroll
  for (int s = 0; s < NSPLIT; ++s) {
    float e = exp2f(Mb[s * SEQ + srow] - M);
    den += Lb[s * SEQ + srow] * e;
    num += bf2f(Op[s * st + idx]) * e;
  }
  out[idx] = num / den;
}

// ---------------------------------------------------------------- launch
extern "C" void kernel_launch(void* const* d_in, const int* in_sizes, int n_in,
                              void* d_out, int out_size, void* d_ws, size_t ws_size,
                              hipStream_t stream) {
  const float* x  = (const float*)d_in[0];
  const float* wq = (const float*)d_in[1];
  const float* wk = (const float*)d_in[2];
  const float* wv = (const float*)d_in[3];
  char* ws = (char*)d_ws;

  // workspace layout (bytes), total exactly 23.25 MiB (proven footprint):
  //  [0,      768K)        Wt bf16 [3][128][1024]
  //  [768K,   +2M)         Q  bf16 [8192][128]   (pre-scaled by QK_SCALE)
  //  [768K+2M,+2M)         K  bf16 [8192][128]
  //  [768K+4M,+2M)         Vt bf16 [128][8192]       (ends 6.75M)
  //  [6.75M,  +256K)       Mb f32 [8][8192]
  //  [6.75M+256K, +256K)   Lb f32 [8][8192]          (ends 7.25M)
  //  [7.25M,  +16M)        Xb bf16 [8192][1024]  ALIASED with
  //                        Op bf16 [8][8192][128] (Xb dead before k_attn)
  const size_t MB = (size_t)1 << 20;
  u16*   Wt = (u16*)(ws);
  u16*   Q  = (u16*)(ws + 768 * 1024);
  u16*   K  = (u16*)(ws + 768 * 1024 + 2 * MB);
  u16*   Vt = (u16*)(ws + 768 * 1024 + 4 * MB);
  float* Mb = (float*)(ws + 768 * 1024 + 6 * MB);
  float* Lb = (float*)(ws + 768 * 1024 + 6 * MB + 256 * 1024);
  u16*   Xb = (u16*)(ws + 7 * MB + 256 * 1024);
  u16*   Op = (u16*)(ws + 7 * MB + 256 * 1024);
  float* out = (float*)d_out;

  k_wtrans<<<dim3((DIN * DOUT) / 256, 3), 256, 0, stream>>>(wq, wk, wv, Wt);
  k_xcast<<<dim3((SEQ * DIN) / (256 * 8)), 256, 0, stream>>>(x, Xb);
  k_gemm<<<dim3(SEQ / 64, 4), 256, 0, stream>>>(Xb, Wt, Q, K, Vt);
  k_attn<<<dim3((SEQ / QTILE) * NSPLIT), 512, 0, stream>>>(Q, K, Vt, Op, Mb, Lb);
  k_combine<<<dim3((SEQ * DOUT) / 256), 256, 0, stream>>>(Op, Mb, Lb, out);
}

// Round 10
// 90.912 us; speedup vs baseline: 1.0155x; 1.0155x over previous
//
#include <hip/hip_runtime.h>
#include <cstdint>

#define SEQ    8192
#define DIN    1024
#define DOUT   128
#define NSPLIT 8
#define KVTILE 64
#define QTILE  128
// Q is pre-scaled by 1/sqrt(128) * log2(e) at the QKV GEMM epilogue, so the
// attn kernel works entirely in log2-units (exp2, no LOG2E muls).
#define QK_SCALE 0.1275174246f
#define RESCALE_THR 8.0f

typedef unsigned short u16;
typedef __bf16 bf16x8 __attribute__((ext_vector_type(8)));
typedef float  f32x4  __attribute__((ext_vector_type(4)));
typedef float  f32x16 __attribute__((ext_vector_type(16)));
typedef unsigned short u16x8 __attribute__((ext_vector_type(8)));
typedef unsigned short u16x4 __attribute__((ext_vector_type(4)));

// f32 -> bf16 via native cast (compiler emits v_cvt_pk_bf16_f32, RNE)
__device__ __forceinline__ u16 bfc(float f) {
  return __builtin_bit_cast(u16, (__bf16)f);
}
__device__ __forceinline__ float bf2f(u16 u) {
  union { uint32_t u; float f; } c; c.u = ((uint32_t)u) << 16; return c.f;
}

__device__ __forceinline__ bf16x8 ldsu8(const u16* base, int byteoff) {
  return __builtin_bit_cast(bf16x8,
    *reinterpret_cast<const u16x8*>(reinterpret_cast<const char*>(base) + byteoff));
}
__device__ __forceinline__ bf16x8 glbu8(const u16* p) {
  return __builtin_bit_cast(bf16x8, *reinterpret_cast<const u16x8*>(p));
}

// async global->LDS DMA, 16B per lane; LDS dest = wave-uniform base + lane*16.
__device__ __forceinline__ void gload_lds16(const void* g, void* l) {
  __builtin_amdgcn_global_load_lds(
      (const __attribute__((address_space(1))) void*)g,
      (__attribute__((address_space(3))) void*)l, 16, 0, 0);
}

// ---------------------------------------------------------------- kernel 0
// W [1024][128] fp32  ->  Wt [3][128][1024] bf16 (transposed)
__global__ __launch_bounds__(256) void k_wtrans(const float* __restrict__ wq,
                                                const float* __restrict__ wk,
                                                const float* __restrict__ wv,
                                                u16* __restrict__ Wt) {
  const float* w = (blockIdx.y == 0) ? wq : (blockIdx.y == 1) ? wk : wv;
  int idx = blockIdx.x * 256 + threadIdx.x;      // over DIN*DOUT
  int k = idx >> 7, n = idx & 127;
  Wt[(size_t)blockIdx.y * (DOUT * DIN) + (size_t)n * DIN + k] = bfc(w[idx]);
}

// ---------------------------------------------------------------- kernel 0b
// X fp32 [8192][1024] -> Xb bf16 [8192][1024], coalesced. 8 elems/thread.
__global__ __launch_bounds__(256) void k_xcast(const float* __restrict__ x,
                                               u16* __restrict__ Xb) {
  size_t base = ((size_t)blockIdx.x * 256 + threadIdx.x) * 8;
  float4 lo = *reinterpret_cast<const float4*>(x + base);
  float4 hi = *reinterpret_cast<const float4*>(x + base + 4);
  u16x8 v = { bfc(lo.x), bfc(lo.y), bfc(lo.z), bfc(lo.w),
              bfc(hi.x), bfc(hi.y), bfc(hi.z), bfc(hi.w) };
  *reinterpret_cast<u16x8*>(Xb + base) = v;
}

// ---------------------------------------------------------------- kernel 1
// GEMM C[8192][384] = Xb[8192][1024] * Wt^T.  (byte-identical to round 7)
__global__ __launch_bounds__(256, 2) void k_gemm(const u16* __restrict__ Xb,
                                                 const u16* __restrict__ Wt,
                                                 u16* __restrict__ Q,
                                                 u16* __restrict__ K,
                                                 u16* __restrict__ Vt) {
  __shared__ __attribute__((aligned(16))) u16 As[2][64 * 128];   // 2x16 KB
  __shared__ __attribute__((aligned(16))) u16 Bs[2][96 * 128];   // 2x24 KB
  const int tid  = threadIdx.x;
  const int lane = tid & 63, wave = tid >> 6;
  const int lm   = lane & 15, g = lane >> 4;
  const int wm   = wave >> 1, wn = wave & 1;     // 2x2 wave grid
  const int m0   = blockIdx.x * 64;
  const int n0   = blockIdx.y * 96;
  const int swzr = (lm & 7) << 4;

  const int trow = tid >> 4;                     // 0..15
  const int tswz = ((tid & 15) << 4) ^ ((trow & 7) << 4);
  const char* baseA = (const char*)Xb + (size_t)(m0 + trow) * 2048 + tswz;
  const char* baseB = (const char*)Wt + (size_t)(n0 + trow) * 2048 + tswz;

  auto stage = [&](int buf, int kc) {
    const int kb = kc * 256;                     // 128 k * 2B
#pragma unroll
    for (int i = 0; i < 4; ++i)                  // A: 64 rows = 4 issues
      gload_lds16(baseA + kb + i * 32768, &As[buf][i * 2048 + wave * 512]);
#pragma unroll
    for (int j = 0; j < 6; ++j)                  // B: 96 rows = 6 issues
      gload_lds16(baseB + kb + j * 32768, &Bs[buf][j * 2048 + wave * 512]);
  };

  f32x4 acc[2][3];
#pragma unroll
  for (int s = 0; s < 2; ++s)
#pragma unroll
    for (int nb = 0; nb < 3; ++nb) acc[s][nb] = (f32x4){0.f, 0.f, 0.f, 0.f};

  auto compute = [&](int buf) {
    const u16* As_ = As[buf];
    const u16* Bs_ = Bs[buf];
    bf16x8 a[2][4], b[3][4];
#pragma unroll
    for (int s = 0; s < 2; ++s)
#pragma unroll
      for (int t = 0; t < 4; ++t)
        a[s][t] = ldsu8(As_, (wm * 32 + s * 16 + lm) * 256 +
                             ((t * 64 + 16 * g) ^ swzr));
#pragma unroll
    for (int nb = 0; nb < 3; ++nb)
#pragma unroll
      for (int t = 0; t < 4; ++t)
        b[nb][t] = ldsu8(Bs_, (wn * 48 + nb * 16 + lm) * 256 +
                              ((t * 64 + 16 * g) ^ swzr));
#pragma unroll
    for (int s = 0; s < 2; ++s)
#pragma unroll
      for (int nb = 0; nb < 3; ++nb)
#pragma unroll
        for (int t = 0; t < 4; ++t)
          acc[s][nb] = __builtin_amdgcn_mfma_f32_16x16x32_bf16(
              a[s][t], b[nb][t], acc[s][nb], 0, 0, 0);
  };

  stage(0, 0);
  asm volatile("s_waitcnt vmcnt(0)" ::: "memory");
  __syncthreads();

#pragma unroll
  for (int kc = 0; kc < 8; kc += 2) {
    if (kc + 1 < 8) stage(1, kc + 1);
    compute(0);
    asm volatile("s_waitcnt vmcnt(0)" ::: "memory");
    __syncthreads();
    if (kc + 2 < 8) stage(0, kc + 2);
    compute(1);
    asm volatile("s_waitcnt vmcnt(0)" ::: "memory");
    __syncthreads();
  }

  // epilogue: C/D layout col=lane&15, row=(lane>>4)*4+reg  [HW-verified]
#pragma unroll
  for (int s = 0; s < 2; ++s)
#pragma unroll
    for (int nb = 0; nb < 3; ++nb) {
      int n = n0 + wn * 48 + nb * 16 + lm;
      int which = n >> 7, col = n & 127;         // uniform per nb
#pragma unroll
      for (int r = 0; r < 4; ++r) {
        int m = m0 + wm * 32 + s * 16 + g * 4 + r;
        if (which == 0)       Q[(size_t)m * DOUT + col] = bfc(acc[s][nb][r] * QK_SCALE);
        else if (which == 1)  K[(size_t)m * DOUT + col] = bfc(acc[s][nb][r]);
        else                  Vt[(size_t)col * SEQ + m] = bfc(acc[s][nb][r]);
      }
    }
}

// ---------------------------------------------------------------- kernel 2
// Flash attention partials — 32x32x16 MFMA variant (LDS-BW fix).
// Diagnosis r9: kernel is LDS-read-throughput-bound (each wave reads the
// whole K/V tile per iter).  mfma_32x32x16 reads the same 16B/lane per
// operand but does 2x the FLOPs -> wave owns 32 q-rows at the same LDS
// volume.  Block 256 (4 waves x 32 q), QTILE=128, KV-tile 64 dbuf, grid
// 512 flat (split = bid&7, XCD-local).  LDS 80 KB -> 2 blocks/CU.
// Layouts: C/D 32x32 [HW-verified]: col=lane&31, row=(reg&3)+8*(reg>>2)
// +4*(lane>>5).  A/B k-map (self-consistent both sides): k=8*(lane>>5)+e.
__global__ __launch_bounds__(256, 2) void k_attn(const u16* __restrict__ Q,
                                                 const u16* __restrict__ K,
                                                 const u16* __restrict__ Vt,
                                                 u16* __restrict__ Op,
                                                 float* __restrict__ Mb,
                                                 float* __restrict__ Lb) {
  __shared__ __attribute__((aligned(16))) u16 Ks[2][64 * 128];    // 2x16 KB
  __shared__ __attribute__((aligned(16))) u16 Vts[2][128 * 64];   // 2x16 KB
  __shared__ __attribute__((aligned(16))) u16 Ps[4][32 * 64];     //  16 KB
  const int tid  = threadIdx.x;
  const int lane = tid & 63, wave = tid >> 6;       // wave 0..3
  const int l31  = lane & 31, h = lane >> 5;
  const int bid  = blockIdx.x;
  const int split = bid & 7;                        // XCD-local split
  const int m0   = (bid >> 3) * QTILE;
  const int kvbase = split * (SEQ / NSPLIT);
  const int NIT = (SEQ / NSPLIT) / KVTILE;          // 16

  // STAGE (r5 geometry, 4 waves): wave w stages K rows [w*16,+16) and
  // Vt rows [w*32,+32); LDS linear, global source pre-swizzled (XOR invol.)
  auto stage = [&](int buf, int kv0) {
#pragma unroll
    for (int i = 0; i < 4; ++i) {
      int krow = wave * 16 + i * 4 + (lane >> 4);
      const char* gk = (const char*)K + ((size_t)(kv0 + krow) << 8) +
                       (((lane & 15) << 4) ^ ((krow & 7) << 4));
      gload_lds16(gk, &Ks[buf][wave * 2048 + i * 512]);
      int vrow = wave * 32 + i * 8 + (lane >> 3);
      const char* gv = (const char*)Vt + (size_t)vrow * (SEQ * 2) +
                       (size_t)kv0 * 2 +
                       (((lane & 7) << 4) ^ ((vrow & 7) << 4));
      gload_lds16(gv, &Vts[buf][wave * 2048 + i * 512]);
    }
  };

  // Q fragments: q-row = m0 + wave*32 + l31; k-elems t*16 + 8h + e
  bf16x8 qf[8];
  stage(0, kvbase);
  {
    const u16* qp = Q + (size_t)(m0 + wave * 32 + l31) * DOUT + 8 * h;
#pragma unroll
    for (int t = 0; t < 8; ++t) qf[t] = glbu8(qp + t * 16);
  }
  asm volatile("s_waitcnt vmcnt(0)" ::: "memory");
  __syncthreads();

  f32x16 o[4] = {};              // O[d=db*32+...][q=l31], 64 f32
  float mr = -1e30f, lr = 0.f;   // lane-local; lr = per-lane partial (k-half)

  u16* pw = Ps[wave];
  char* pwb = reinterpret_cast<char*>(pw) + l31 * 128;  // P row q=l31, 128B
  const int pswz = (l31 & 7) << 4;
  int cur = 0;

  for (int it = 0; it < NIT; ++it) {
    if (it + 1 < NIT) stage(cur ^ 1, kvbase + (it + 1) * KVTILE);

    const u16* ks = Ks[cur];
    const u16* vs = Vts[cur];

    // ---- S^T = K Q^T  (A = K rows, B = Q cols; 2 k-blocks x 8 K-steps)
    f32x16 s[2];
    __builtin_amdgcn_s_setprio(1);
#pragma unroll
    for (int kb = 0; kb < 2; ++kb) {
      f32x16 a = {};
      int krow = kb * 32 + l31;
      int rswz = (krow & 7) << 4;
#pragma unroll
      for (int t = 0; t < 8; ++t) {
        bf16x8 kf = ldsu8(ks, krow * 256 + ((t * 32 + 16 * h) ^ rswz));
        a = __builtin_amdgcn_mfma_f32_32x32x16_bf16(kf, qf[t], a, 0, 0, 0);
      }
      s[kb] = a;          // log2-units (Q pre-scaled); lane: q=l31, 16 k-vals
    }
    __builtin_amdgcn_s_setprio(0);

    // ---- row max: 31-fmax in-lane tree + 1 shuffle (merge k-halves)
    float t8[8];
#pragma unroll
    for (int i = 0; i < 8; ++i)
      t8[i] = fmaxf(fmaxf(s[0][2 * i], s[0][2 * i + 1]),
                    fmaxf(s[1][2 * i], s[1][2 * i + 1]));
    float u0 = fmaxf(fmaxf(t8[0], t8[1]), fmaxf(t8[2], t8[3]));
    float u1 = fmaxf(fmaxf(t8[4], t8[5]), fmaxf(t8[6], t8[7]));
    float rm = fmaxf(u0, u1);
    rm = fmaxf(rm, __shfl_xor(rm, 32));

    if (__any(rm - mr > RESCALE_THR)) {   // first tile + rare growth
      float mn = fmaxf(mr, rm);
      float alpha = exp2f(mr - mn);
      mr = mn;
      lr *= alpha;
#pragma unroll
      for (int db = 0; db < 4; ++db) o[db] *= alpha;
    }

    // ---- P = exp2(S - m); chunk (kb,j): k = kb*32+8j+4h+{0..3}
    float rsum = 0.f;
#pragma unroll
    for (int kb = 0; kb < 2; ++kb)
#pragma unroll
      for (int j = 0; j < 4; ++j) {
        float p0 = exp2f(s[kb][4 * j + 0] - mr);
        float p1 = exp2f(s[kb][4 * j + 1] - mr);
        float p2 = exp2f(s[kb][4 * j + 2] - mr);
        float p3 = exp2f(s[kb][4 * j + 3] - mr);
        u16x4 w = { bfc(p0), bfc(p1), bfc(p2), bfc(p3) };
        *reinterpret_cast<u16x4*>(pwb +
            ((kb * 64 + 16 * j + 8 * h) ^ pswz)) = w;
        rsum += (p0 + p1) + (p2 + p3);
      }
    lr += rsum;                           // cross-lane reduce deferred to end

    asm volatile("s_waitcnt lgkmcnt(0)" ::: "memory");
    __builtin_amdgcn_sched_barrier(0);

    // ---- O^T += V^T P  (A = V^T d-rows, B = P q-cols; 4 kv-steps)
    __builtin_amdgcn_s_setprio(1);
#pragma unroll
    for (int j = 0; j < 4; ++j) {
      bf16x8 pb = ldsu8(pw, l31 * 128 + ((32 * j + 16 * h) ^ pswz));
#pragma unroll
      for (int db = 0; db < 4; ++db) {
        int vrow = db * 32 + l31;
        bf16x8 vb = ldsu8(vs, vrow * 128 +
                              ((32 * j + 16 * h) ^ ((vrow & 7) << 4)));
        o[db] = __builtin_amdgcn_mfma_f32_32x32x16_bf16(vb, pb, o[db], 0, 0, 0);
      }
    }
    __builtin_amdgcn_s_setprio(0);

    asm volatile("s_waitcnt vmcnt(0)" ::: "memory");
    __syncthreads();
    cur ^= 1;
  }

  // ---- epilogue: finish l reduction (merge the two k-half lanes)
  lr += __shfl_xor(lr, 32);

  // store partials: lane holds O[d = db*32+8j+4h+c][q = m0+wave*32+l31]
  const size_t ob = (size_t)split * SEQ * DOUT;
  const int q = m0 + wave * 32 + l31;
#pragma unroll
  for (int db = 0; db < 4; ++db)
#pragma unroll
    for (int j = 0; j < 4; ++j) {
      u16x4 w = { bfc(o[db][4 * j + 0]), bfc(o[db][4 * j + 1]),
                  bfc(o[db][4 * j + 2]), bfc(o[db][4 * j + 3]) };
      *reinterpret_cast<u16x4*>(Op + ob + (size_t)q * DOUT +
                                db * 32 + 8 * j + 4 * h) = w;
    }
  if (h == 0) {
    Mb[split * SEQ + q] = mr;   // log2-units
    Lb[split * SEQ + q] = lr;
  }
}

// ---------------------------------------------------------------- kernel 3
__global__ __launch_bounds__(256) void k_combine(const u16* __restrict__ Op,
                                                 const float* __restrict__ Mb,
                                                 const float* __restrict__ Lb,
                                                 float* __restrict__ out) {
  int idx = blockIdx.x * 256 + threadIdx.x;   // over SEQ*DOUT
  int srow = idx >> 7;
  float M = -1e30f;
#pragma unroll
  for (int s = 0; s < NSPLIT; ++s) M = fmaxf(M, Mb[s * SEQ + srow]);
  float num = 0.f, den = 0.f;
  const size_t st = (size_t)SEQ * DOUT;
#pragma unroll
  for (int s = 0; s < NSPLIT; ++s) {
    float e = exp2f(Mb[s * SEQ + srow] - M);
    den += Lb[s * SEQ + srow] * e;
    num += bf2f(Op[s * st + idx]) * e;
  }
  out[idx] = num / den;
}

// ---------------------------------------------------------------- launch
extern "C" void kernel_launch(void* const* d_in, const int* in_sizes, int n_in,
                              void* d_out, int out_size, void* d_ws, size_t ws_size,
                              hipStream_t stream) {
  const float* x  = (const float*)d_in[0];
  const float* wq = (const float*)d_in[1];
  const float* wk = (const float*)d_in[2];
  const float* wv = (const float*)d_in[3];
  char* ws = (char*)d_ws;

  // workspace layout (bytes), total exactly 23.25 MiB (proven footprint):
  //  [0,      768K)        Wt bf16 [3][128][1024]
  //  [768K,   +2M)         Q  bf16 [8192][128]   (pre-scaled by QK_SCALE)
  //  [768K+2M,+2M)         K  bf16 [8192][128]
  //  [768K+4M,+2M)         Vt bf16 [128][8192]       (ends 6.75M)
  //  [6.75M,  +256K)       Mb f32 [8][8192]
  //  [6.75M+256K, +256K)   Lb f32 [8][8192]          (ends 7.25M)
  //  [7.25M,  +16M)        Xb bf16 [8192][1024]  ALIASED with
  //                        Op bf16 [8][8192][128] (Xb dead before k_attn)
  const size_t MB = (size_t)1 << 20;
  u16*   Wt = (u16*)(ws);
  u16*   Q  = (u16*)(ws + 768 * 1024);
  u16*   K  = (u16*)(ws + 768 * 1024 + 2 * MB);
  u16*   Vt = (u16*)(ws + 768 * 1024 + 4 * MB);
  float* Mb = (float*)(ws + 768 * 1024 + 6 * MB);
  float* Lb = (float*)(ws + 768 * 1024 + 6 * MB + 256 * 1024);
  u16*   Xb = (u16*)(ws + 7 * MB + 256 * 1024);
  u16*   Op = (u16*)(ws + 7 * MB + 256 * 1024);
  float* out = (float*)d_out;

  k_wtrans<<<dim3((DIN * DOUT) / 256, 3), 256, 0, stream>>>(wq, wk, wv, Wt);
  k_xcast<<<dim3((SEQ * DIN) / (256 * 8)), 256, 0, stream>>>(x, Xb);
  k_gemm<<<dim3(SEQ / 64, 4), 256, 0, stream>>>(Xb, Wt, Q, K, Vt);
  k_attn<<<dim3((SEQ / QTILE) * NSPLIT), 256, 0, stream>>>(Q, K, Vt, Op, Mb, Lb);
  k_combine<<<dim3((SEQ * DOUT) / 256), 256, 0, stream>>>(Op, Mb, Lb, out);
}

// Round 11
// 89.880 us; speedup vs baseline: 1.0272x; 1.0115x over previous
//
#include <hip/hip_runtime.h>
#include <cstdint>

#define SEQ    8192
#define DIN    1024
#define DOUT   128
#define NSPLIT 8
#define KVTILE 64
#define QTILE  128
// Q is pre-scaled by 1/sqrt(128) * log2(e) at the QKV GEMM epilogue, so the
// attn kernel works entirely in log2-units (exp2, no LOG2E muls).
#define QK_SCALE 0.1275174246f
#define RESCALE_THR 8.0f

typedef unsigned short u16;
typedef __bf16 bf16x8 __attribute__((ext_vector_type(8)));
typedef float  f32x4  __attribute__((ext_vector_type(4)));
typedef float  f32x16 __attribute__((ext_vector_type(16)));
typedef unsigned short u16x8 __attribute__((ext_vector_type(8)));
typedef unsigned short u16x4 __attribute__((ext_vector_type(4)));
typedef unsigned int u32x2 __attribute__((ext_vector_type(2)));
typedef unsigned int u32x4 __attribute__((ext_vector_type(4)));

// f32 -> bf16 via native cast (compiler emits v_cvt_pk_bf16_f32, RNE)
__device__ __forceinline__ u16 bfc(float f) {
  return __builtin_bit_cast(u16, (__bf16)f);
}
__device__ __forceinline__ float bf2f(u16 u) {
  union { uint32_t u; float f; } c; c.u = ((uint32_t)u) << 16; return c.f;
}

__device__ __forceinline__ bf16x8 ldsu8(const u16* base, int byteoff) {
  return __builtin_bit_cast(bf16x8,
    *reinterpret_cast<const u16x8*>(reinterpret_cast<const char*>(base) + byteoff));
}
__device__ __forceinline__ bf16x8 glbu8(const u16* p) {
  return __builtin_bit_cast(bf16x8, *reinterpret_cast<const u16x8*>(p));
}

// async global->LDS DMA, 16B per lane; LDS dest = wave-uniform base + lane*16.
__device__ __forceinline__ void gload_lds16(const void* g, void* l) {
  __builtin_amdgcn_global_load_lds(
      (const __attribute__((address_space(1))) void*)g,
      (__attribute__((address_space(3))) void*)l, 16, 0, 0);
}

// ---------------------------------------------------------------- kernel 0
// W [1024][128] fp32  ->  Wt [3][128][1024] bf16 (transposed)
__global__ __launch_bounds__(256) void k_wtrans(const float* __restrict__ wq,
                                                const float* __restrict__ wk,
                                                const float* __restrict__ wv,
                                                u16* __restrict__ Wt) {
  const float* w = (blockIdx.y == 0) ? wq : (blockIdx.y == 1) ? wk : wv;
  int idx = blockIdx.x * 256 + threadIdx.x;      // over DIN*DOUT
  int k = idx >> 7, n = idx & 127;
  Wt[(size_t)blockIdx.y * (DOUT * DIN) + (size_t)n * DIN + k] = bfc(w[idx]);
}

// ---------------------------------------------------------------- kernel 0b
// X fp32 [8192][1024] -> Xb bf16 [8192][1024], coalesced. 8 elems/thread.
__global__ __launch_bounds__(256) void k_xcast(const float* __restrict__ x,
                                               u16* __restrict__ Xb) {
  size_t base = ((size_t)blockIdx.x * 256 + threadIdx.x) * 8;
  float4 lo = *reinterpret_cast<const float4*>(x + base);
  float4 hi = *reinterpret_cast<const float4*>(x + base + 4);
  u16x8 v = { bfc(lo.x), bfc(lo.y), bfc(lo.z), bfc(lo.w),
              bfc(hi.x), bfc(hi.y), bfc(hi.z), bfc(hi.w) };
  *reinterpret_cast<u16x8*>(Xb + base) = v;
}

// ---------------------------------------------------------------- kernel 1
// GEMM C[8192][384] = Xb[8192][1024] * Wt^T.  (byte-identical to round 7)
__global__ __launch_bounds__(256, 2) void k_gemm(const u16* __restrict__ Xb,
                                                 const u16* __restrict__ Wt,
                                                 u16* __restrict__ Q,
                                                 u16* __restrict__ K,
                                                 u16* __restrict__ Vt) {
  __shared__ __attribute__((aligned(16))) u16 As[2][64 * 128];   // 2x16 KB
  __shared__ __attribute__((aligned(16))) u16 Bs[2][96 * 128];   // 2x24 KB
  const int tid  = threadIdx.x;
  const int lane = tid & 63, wave = tid >> 6;
  const int lm   = lane & 15, g = lane >> 4;
  const int wm   = wave >> 1, wn = wave & 1;     // 2x2 wave grid
  const int m0   = blockIdx.x * 64;
  const int n0   = blockIdx.y * 96;
  const int swzr = (lm & 7) << 4;

  const int trow = tid >> 4;                     // 0..15
  const int tswz = ((tid & 15) << 4) ^ ((trow & 7) << 4);
  const char* baseA = (const char*)Xb + (size_t)(m0 + trow) * 2048 + tswz;
  const char* baseB = (const char*)Wt + (size_t)(n0 + trow) * 2048 + tswz;

  auto stage = [&](int buf, int kc) {
    const int kb = kc * 256;                     // 128 k * 2B
#pragma unroll
    for (int i = 0; i < 4; ++i)                  // A: 64 rows = 4 issues
      gload_lds16(baseA + kb + i * 32768, &As[buf][i * 2048 + wave * 512]);
#pragma unroll
    for (int j = 0; j < 6; ++j)                  // B: 96 rows = 6 issues
      gload_lds16(baseB + kb + j * 32768, &Bs[buf][j * 2048 + wave * 512]);
  };

  f32x4 acc[2][3];
#pragma unroll
  for (int s = 0; s < 2; ++s)
#pragma unroll
    for (int nb = 0; nb < 3; ++nb) acc[s][nb] = (f32x4){0.f, 0.f, 0.f, 0.f};

  auto compute = [&](int buf) {
    const u16* As_ = As[buf];
    const u16* Bs_ = Bs[buf];
    bf16x8 a[2][4], b[3][4];
#pragma unroll
    for (int s = 0; s < 2; ++s)
#pragma unroll
      for (int t = 0; t < 4; ++t)
        a[s][t] = ldsu8(As_, (wm * 32 + s * 16 + lm) * 256 +
                             ((t * 64 + 16 * g) ^ swzr));
#pragma unroll
    for (int nb = 0; nb < 3; ++nb)
#pragma unroll
      for (int t = 0; t < 4; ++t)
        b[nb][t] = ldsu8(Bs_, (wn * 48 + nb * 16 + lm) * 256 +
                              ((t * 64 + 16 * g) ^ swzr));
#pragma unroll
    for (int s = 0; s < 2; ++s)
#pragma unroll
      for (int nb = 0; nb < 3; ++nb)
#pragma unroll
        for (int t = 0; t < 4; ++t)
          acc[s][nb] = __builtin_amdgcn_mfma_f32_16x16x32_bf16(
              a[s][t], b[nb][t], acc[s][nb], 0, 0, 0);
  };

  stage(0, 0);
  asm volatile("s_waitcnt vmcnt(0)" ::: "memory");
  __syncthreads();

#pragma unroll
  for (int kc = 0; kc < 8; kc += 2) {
    if (kc + 1 < 8) stage(1, kc + 1);
    compute(0);
    asm volatile("s_waitcnt vmcnt(0)" ::: "memory");
    __syncthreads();
    if (kc + 2 < 8) stage(0, kc + 2);
    compute(1);
    asm volatile("s_waitcnt vmcnt(0)" ::: "memory");
    __syncthreads();
  }

  // epilogue: C/D layout col=lane&15, row=(lane>>4)*4+reg  [HW-verified]
#pragma unroll
  for (int s = 0; s < 2; ++s)
#pragma unroll
    for (int nb = 0; nb < 3; ++nb) {
      int n = n0 + wn * 48 + nb * 16 + lm;
      int which = n >> 7, col = n & 127;         // uniform per nb
#pragma unroll
      for (int r = 0; r < 4; ++r) {
        int m = m0 + wm * 32 + s * 16 + g * 4 + r;
        if (which == 0)       Q[(size_t)m * DOUT + col] = bfc(acc[s][nb][r] * QK_SCALE);
        else if (which == 1)  K[(size_t)m * DOUT + col] = bfc(acc[s][nb][r]);
        else                  Vt[(size_t)col * SEQ + m] = bfc(acc[s][nb][r]);
      }
    }
}

// ---------------------------------------------------------------- kernel 2
// Flash attention partials — 32x32x16 + T12 in-register P.
// r10 post-mortem: iter critical path is the convoy (P ds_write -> lgkm
// drain -> P ds_read serializes softmax vs PV; V-reads can't overlap).
// Fix: P never touches LDS.  Swapped QK^T leaves P lane-local; PV's
// B-fragment only needs the lane<->lane+32 half-swap:
//   A0=pk(e0,e1) A1=pk(e2,e3) (rr=0), B0=pk(e4,e5) B1=pk(e6,e7) (rr=1)
//   swap(A0,B0) -> {e01-word, e45-word}; swap(A1,B1) -> {e23, e67}
//   frag u32[4] = {r01.x, r23.x, r01.y, r23.y}   (derivation in journal)
// Removes 8 ds_write_b64 + 4 ds_read_b128 + lgkm-drain per wave-iter;
// V-reads now dependence-free (overlap softmax).  LDS 64 KB.
__global__ __launch_bounds__(256, 2) void k_attn(const u16* __restrict__ Q,
                                                 const u16* __restrict__ K,
                                                 const u16* __restrict__ Vt,
                                                 u16* __restrict__ Op,
                                                 float* __restrict__ Mb,
                                                 float* __restrict__ Lb) {
  __shared__ __attribute__((aligned(16))) u16 Ks[2][64 * 128];    // 2x16 KB
  __shared__ __attribute__((aligned(16))) u16 Vts[2][128 * 64];   // 2x16 KB
  const int tid  = threadIdx.x;
  const int lane = tid & 63, wave = tid >> 6;       // wave 0..3
  const int l31  = lane & 31, h = lane >> 5;
  const int bid  = blockIdx.x;
  const int split = bid & 7;                        // XCD-local split
  const int m0   = (bid >> 3) * QTILE;
  const int kvbase = split * (SEQ / NSPLIT);
  const int NIT = (SEQ / NSPLIT) / KVTILE;          // 16

  // STAGE: wave w stages K rows [w*16,+16) and Vt rows [w*32,+32);
  // LDS linear, global source pre-swizzled (XOR involution, same on read).
  auto stage = [&](int buf, int kv0) {
#pragma unroll
    for (int i = 0; i < 4; ++i) {
      int krow = wave * 16 + i * 4 + (lane >> 4);
      const char* gk = (const char*)K + ((size_t)(kv0 + krow) << 8) +
                       (((lane & 15) << 4) ^ ((krow & 7) << 4));
      gload_lds16(gk, &Ks[buf][wave * 2048 + i * 512]);
      int vrow = wave * 32 + i * 8 + (lane >> 3);
      const char* gv = (const char*)Vt + (size_t)vrow * (SEQ * 2) +
                       (size_t)kv0 * 2 +
                       (((lane & 7) << 4) ^ ((vrow & 7) << 4));
      gload_lds16(gv, &Vts[buf][wave * 2048 + i * 512]);
    }
  };

  // Q fragments: q-row = m0 + wave*32 + l31; k-elems t*16 + 8h + e
  bf16x8 qf[8];
  stage(0, kvbase);
  {
    const u16* qp = Q + (size_t)(m0 + wave * 32 + l31) * DOUT + 8 * h;
#pragma unroll
    for (int t = 0; t < 8; ++t) qf[t] = glbu8(qp + t * 16);
  }
  asm volatile("s_waitcnt vmcnt(0)" ::: "memory");
  __syncthreads();

  f32x16 o[4] = {};              // O[d=db*32+...][q=l31], 64 f32
  float mr = -1e30f, lr = 0.f;   // lane-local; lr = per-lane partial (k-half)

  int cur = 0;

  for (int it = 0; it < NIT; ++it) {
    if (it + 1 < NIT) stage(cur ^ 1, kvbase + (it + 1) * KVTILE);

    const u16* ks = Ks[cur];
    const u16* vs = Vts[cur];

    // ---- S^T = K Q^T  (A = K rows, B = Q cols; 2 k-blocks x 8 K-steps)
    f32x16 s[2];
    __builtin_amdgcn_s_setprio(1);
#pragma unroll
    for (int kb = 0; kb < 2; ++kb) {
      f32x16 a = {};
      int krow = kb * 32 + l31;
      int rswz = (krow & 7) << 4;
#pragma unroll
      for (int t = 0; t < 8; ++t) {
        bf16x8 kf = ldsu8(ks, krow * 256 + ((t * 32 + 16 * h) ^ rswz));
        a = __builtin_amdgcn_mfma_f32_32x32x16_bf16(kf, qf[t], a, 0, 0, 0);
      }
      s[kb] = a;          // log2-units (Q pre-scaled); lane: q=l31, 16 k-vals
    }
    __builtin_amdgcn_s_setprio(0);

    // ---- row max: 31-fmax in-lane tree + 1 shuffle (merge k-halves)
    float t8[8];
#pragma unroll
    for (int i = 0; i < 8; ++i)
      t8[i] = fmaxf(fmaxf(s[0][2 * i], s[0][2 * i + 1]),
                    fmaxf(s[1][2 * i], s[1][2 * i + 1]));
    float u0 = fmaxf(fmaxf(t8[0], t8[1]), fmaxf(t8[2], t8[3]));
    float u1 = fmaxf(fmaxf(t8[4], t8[5]), fmaxf(t8[6], t8[7]));
    float rm = fmaxf(u0, u1);
    rm = fmaxf(rm, __shfl_xor(rm, 32));

    if (__any(rm - mr > RESCALE_THR)) {   // first tile + rare growth
      float mn = fmaxf(mr, rm);
      float alpha = exp2f(mr - mn);
      mr = mn;
      lr *= alpha;
#pragma unroll
      for (int db = 0; db < 4; ++db) o[db] *= alpha;
    }

    // ---- P = exp2(S - m) in registers; per j-step: pack + half-swap
    //      then O^T += V^T P immediately (no LDS for P, no drain).
    float rsum = 0.f;
#pragma unroll
    for (int j = 0; j < 4; ++j) {
      const int kb = j >> 1;
      const int base = (j & 1) * 8;     // regs [base, base+8) of s[kb]
      float e0 = exp2f(s[kb][base + 0] - mr);
      float e1 = exp2f(s[kb][base + 1] - mr);
      float e2 = exp2f(s[kb][base + 2] - mr);
      float e3 = exp2f(s[kb][base + 3] - mr);
      float e4 = exp2f(s[kb][base + 4] - mr);
      float e5 = exp2f(s[kb][base + 5] - mr);
      float e6 = exp2f(s[kb][base + 6] - mr);
      float e7 = exp2f(s[kb][base + 7] - mr);
      rsum += ((e0 + e1) + (e2 + e3)) + ((e4 + e5) + (e6 + e7));
      u16x4 wa = { bfc(e0), bfc(e1), bfc(e2), bfc(e3) };   // rr=0 pair-packs
      u16x4 wb = { bfc(e4), bfc(e5), bfc(e6), bfc(e7) };   // rr=1 pair-packs
      u32x2 A = __builtin_bit_cast(u32x2, wa);
      u32x2 B = __builtin_bit_cast(u32x2, wb);
      u32x2 r01 = __builtin_amdgcn_permlane32_swap(A.x, B.x, false, false);
      u32x2 r23 = __builtin_amdgcn_permlane32_swap(A.y, B.y, false, false);
      u32x4 fr = { r01.x, r23.x, r01.y, r23.y };
      bf16x8 pb = __builtin_bit_cast(bf16x8, fr);
      __builtin_amdgcn_s_setprio(1);
#pragma unroll
      for (int db = 0; db < 4; ++db) {
        int vrow = db * 32 + l31;
        bf16x8 vb = ldsu8(vs, vrow * 128 +
                              ((32 * j + 16 * h) ^ ((vrow & 7) << 4)));
        o[db] = __builtin_amdgcn_mfma_f32_32x32x16_bf16(vb, pb, o[db], 0, 0, 0);
      }
      __builtin_amdgcn_s_setprio(0);
    }
    lr += rsum;                           // cross-lane reduce deferred to end

    asm volatile("s_waitcnt vmcnt(0)" ::: "memory");
    __syncthreads();
    cur ^= 1;
  }

  // ---- epilogue: finish l reduction (merge the two k-half lanes)
  lr += __shfl_xor(lr, 32);

  // store partials: lane holds O[d = db*32+8j+4h+c][q = m0+wave*32+l31]
  const size_t ob = (size_t)split * SEQ * DOUT;
  const int q = m0 + wave * 32 + l31;
#pragma unroll
  for (int db = 0; db < 4; ++db)
#pragma unroll
    for (int j = 0; j < 4; ++j) {
      u16x4 w = { bfc(o[db][4 * j + 0]), bfc(o[db][4 * j + 1]),
                  bfc(o[db][4 * j + 2]), bfc(o[db][4 * j + 3]) };
      *reinterpret_cast<u16x4*>(Op + ob + (size_t)q * DOUT +
                                db * 32 + 8 * j + 4 * h) = w;
    }
  if (h == 0) {
    Mb[split * SEQ + q] = mr;   // log2-units
    Lb[split * SEQ + q] = lr;
  }
}

// ---------------------------------------------------------------- kernel 3
__global__ __launch_bounds__(256) void k_combine(const u16* __restrict__ Op,
                                                 const float* __restrict__ Mb,
                                                 const float* __restrict__ Lb,
                                                 float* __restrict__ out) {
  int idx = blockIdx.x * 256 + threadIdx.x;   // over SEQ*DOUT
  int srow = idx >> 7;
  float M = -1e30f;
#pragma unroll
  for (int s = 0; s < NSPLIT; ++s) M = fmaxf(M, Mb[s * SEQ + srow]);
  float num = 0.f, den = 0.f;
  const size_t st = (size_t)SEQ * DOUT;
#pragma unroll
  for (int s = 0; s < NSPLIT; ++s) {
    float e = exp2f(Mb[s * SEQ + srow] - M);
    den += Lb[s * SEQ + srow] * e;
    num += bf2f(Op[s * st + idx]) * e;
  }
  out[idx] = num / den;
}

// ---------------------------------------------------------------- launch
extern "C" void kernel_launch(void* const* d_in, const int* in_sizes, int n_in,
                              void* d_out, int out_size, void* d_ws, size_t ws_size,
                              hipStream_t stream) {
  const float* x  = (const float*)d_in[0];
  const float* wq = (const float*)d_in[1];
  const float* wk = (const float*)d_in[2];
  const float* wv = (const float*)d_in[3];
  char* ws = (char*)d_ws;

  // workspace layout (bytes), total exactly 23.25 MiB (proven footprint):
  //  [0,      768K)        Wt bf16 [3][128][1024]
  //  [768K,   +2M)         Q  bf16 [8192][128]   (pre-scaled by QK_SCALE)
  //  [768K+2M,+2M)         K  bf16 [8192][128]
  //  [768K+4M,+2M)         Vt bf16 [128][8192]       (ends 6.75M)
  //  [6.75M,  +256K)       Mb f32 [8][8192]
  //  [6.75M+256K, +256K)   Lb f32 [8][8192]          (ends 7.25M)
  //  [7.25M,  +16M)        Xb bf16 [8192][1024]  ALIASED with
  //                        Op bf16 [8][8192][128] (Xb dead before k_attn)
  const size_t MB = (size_t)1 << 20;
  u16*   Wt = (u16*)(ws);
  u16*   Q  = (u16*)(ws + 768 * 1024);
  u16*   K  = (u16*)(ws + 768 * 1024 + 2 * MB);
  u16*   Vt = (u16*)(ws + 768 * 1024 + 4 * MB);
  float* Mb = (float*)(ws + 768 * 1024 + 6 * MB);
  float* Lb = (float*)(ws + 768 * 1024 + 6 * MB + 256 * 1024);
  u16*   Xb = (u16*)(ws + 7 * MB + 256 * 1024);
  u16*   Op = (u16*)(ws + 7 * MB + 256 * 1024);
  float* out = (float*)d_out;

  k_wtrans<<<dim3((DIN * DOUT) / 256, 3), 256, 0, stream>>>(wq, wk, wv, Wt);
  k_xcast<<<dim3((SEQ * DIN) / (256 * 8)), 256, 0, stream>>>(x, Xb);
  k_gemm<<<dim3(SEQ / 64, 4), 256, 0, stream>>>(Xb, Wt, Q, K, Vt);
  k_attn<<<dim3((SEQ / QTILE) * NSPLIT), 256, 0, stream>>>(Q, K, Vt, Op, Mb, Lb);
  k_combine<<<dim3((SEQ * DOUT) / 256), 256, 0, stream>>>(Op, Mb, Lb, out);
}